// Round 17
// baseline (495.413 us; speedup 1.0000x reference)
//
#include <hip/hip_runtime.h>

// GTA model: GCN(2-hop) -> 3x transformer encoder -> 10-step AR predictor.
// R31: k_attn14 = 1 q-set/wave x 8 waves (512 thr). Register arithmetic:
// 1 set = ~80 arch + 28 AGPR ~ 110 <= 128 -> 4 waves/SIMD (2x occupancy vs
// attn12's 156-reg 2-set). Cost: shared-tile LDS a-reads feed 1 MFMA not 2
// (LDS busy ~34%->~68%, still under pipe limit). Same proven two-barrier
// vmcnt contract; staging split over 8 waves (wave7 stages no xt -> its
// vmcnt(2) is a no-op, contract shape identical). Q-proj scratch spans both
// xr buffers; xr(0) staged after Q-proj behind a barrier (once/block).
// LDS 47104 -> 2 blocks/CU. Rest identical to R30 (461.2us verified).

#define ROWS 24576   // C*T = 32*768

// workspace offsets (floats)
#define OFF_ADJ   0L
#define OFF_X0    1024L
#define OFF_X1    (OFF_X0 + 2457600L)
#define OFF_XROW  (OFF_X1 + 3932160L)        // 24576*128 bf16 = 1572864 floats
#define OFF_XT    (OFF_XROW + 1572864L)
#define OFF_WBF   (OFF_XT + 1572864L)        // 24576*512 bf16 = 6291456 floats
#define OFF_MHT   (OFF_WBF + 6291456L)       // 15*128*128 bf16 = 122880 floats
#define OFF_USTT  (OFF_MHT + 122880L)        // 3*128*512 bf16 = 98304 floats
#define OFF_MP    (OFF_USTT + 98304L)        // 100*100 fp32
#define OFF_C0    (OFF_MP + 10000L)          // 100 fp32 (pad to 128)
#define OFF_F1WT  (OFF_C0 + 128L)            // 3*64*128 bf16 = 12288 floats
#define OFF_F2WT  (OFF_F1WT + 12288L)        // 3*112*64 bf16 = 10752 floats
#define OFF_GW1T  (OFF_F2WT + 10752L)        // 64*128 bf16 = 4096 floats
#define OFF_GW2T  (OFF_GW1T + 4096L)         // 112*64 bf16 = 3584 floats
// GCN scratch inside OFF_X1 region:
//   g   bf16 24576*64  @ OFF_X1 ; hid bf16 24576*64 @ +786432 ; h2 bf16 24576*128 @ +1572864

typedef __attribute__((ext_vector_type(8))) short short8;
typedef __attribute__((ext_vector_type(4))) short short4v;
typedef __attribute__((ext_vector_type(4))) float float4v;
typedef __attribute__((ext_vector_type(2))) unsigned int uint2v;
typedef __attribute__((ext_vector_type(4))) unsigned int uint4v;

__device__ inline unsigned short f2bf(float f) {
    unsigned u = __builtin_bit_cast(unsigned, f);
    return (unsigned short)((u + 0x7fffu + ((u >> 16) & 1u)) >> 16);
}
// packed f32x2 -> bf16x2, RNE — single v_cvt_pk_bf16_f32.
__device__ inline unsigned pk2bf(float lo, float hi) {
    unsigned r;
    asm("v_cvt_pk_bf16_f32 %0, %1, %2" : "=v"(r) : "v"(lo), "v"(hi));
    return r;
}
// LDS store of 2 packed bf16x2 words, short-typed (TBAA-consistent with loads).
__device__ inline void st4s(short* p, unsigned a, unsigned b) {
    *(short4v*)p = __builtin_bit_cast(short4v, (uint2v){a, b});
}
__device__ inline float bf2f(unsigned short v) {
    return __builtin_bit_cast(float, ((unsigned)v) << 16);
}
// async global->LDS DMA, 16B per lane; LDS dest = wave-uniform base + lane*16
__device__ inline void gload16(const short* g, short* l) {
    __builtin_amdgcn_global_load_lds((const __attribute__((address_space(1))) void*)g,
                                     (__attribute__((address_space(3))) void*)l, 16, 0, 0);
}
// xT key-dim permutation: within each 64-key block, quad q -> slot
// (q&8)|((q&3)<<1)|((q>>2)&1); chunk j then holds quads (j, 4+j).
__device__ inline int permt(int t) {
    int tl = t & 63, q = tl >> 2, r = tl & 3;
    int pos = (q & 8) | ((q & 3) << 1) | ((q >> 2) & 1);
    return (t & ~63) | (pos << 2) | r;
}

// ---------------- precompute: MhT, UstT, f1wT, f2wT, gw1T, gw2T (bf16 padded), Mpred, c0, adjh ----
__global__ void __launch_bounds__(256) k_mu2(const float* __restrict__ wq, const float* __restrict__ wk,
                                             const float* __restrict__ wv, const float* __restrict__ wm,
                                             const float* __restrict__ l1w, const float* __restrict__ l1b,
                                             const float* __restrict__ l2w, const float* __restrict__ l2b,
                                             const float* __restrict__ f1w, const float* __restrict__ f2w,
                                             const float* __restrict__ A,
                                             const float* __restrict__ gw1, const float* __restrict__ gw2,
                                             unsigned short* __restrict__ MhT, unsigned short* __restrict__ UstT,
                                             float* __restrict__ Mp, float* __restrict__ c0v,
                                             unsigned short* __restrict__ f1wT, unsigned short* __restrict__ f2wT,
                                             float* __restrict__ adjh,
                                             unsigned short* __restrict__ gw1T, unsigned short* __restrict__ gw2T) {
    int bi = blockIdx.x, tid = threadIdx.x;
    if (bi < 480) {
        int mat = bi >> 4, sub = bi & 15;
        int mode = mat / 15, idx = mat % 15, l = idx / 5, h = idx % 5;
        const float* Asrc = (mode == 0 ? wq : wv) + (l*5 + h)*10000;
        const float* Bsrc = (mode == 0) ? (wk + (l*5 + h)*10000) : (wm + l*50000 + h*10000);
        int oend = sub*625 + 625;
        for (int o = sub*625 + tid; o < oend; o += 256) {
            int r = o / 100, cix = o - (o/100)*100;
            const float* arow = Asrc + r*100;
            float acc = 0.f;
            if (mode == 0) {
                const float* brow = Bsrc + cix*100;
                float4 s = {0,0,0,0};
                #pragma unroll 5
                for (int e4 = 0; e4 < 25; ++e4) {
                    float4 av = *(const float4*)(arow + e4*4);
                    float4 bv = *(const float4*)(brow + e4*4);
                    s.x += av.x*bv.x; s.y += av.y*bv.y;
                    s.z += av.z*bv.z; s.w += av.w*bv.w;
                }
                acc = (s.x + s.y) + (s.z + s.w);
                MhT[(long)(l*5 + h)*16384 + cix*128 + r] = f2bf(acc * 0.1f);
            } else {
                for (int e = 0; e < 100; ++e) acc += arow[e] * Bsrc[e*100 + cix];
                UstT[(long)l*65536 + (long)cix*512 + h*100 + r] = f2bf(acc);
            }
        }
        if (sub == 0) {   // zero padding
            if (mode == 0) {
                unsigned short* M0 = MhT + (long)(l*5 + h)*16384;
                for (int i = tid; i < 28*128; i += 256) M0[(100 + i/128)*128 + (i%128)] = 0;
                for (int i = tid; i < 100*28; i += 256) M0[(i/28)*128 + 100 + (i%28)] = 0;
            } else if (h == 4) {
                unsigned short* U0 = UstT + (long)l*65536;
                for (int i = tid; i < 28*512; i += 256) U0[(long)(100 + i/512)*512 + (i%512)] = 0;
                for (int i = tid; i < 100*12; i += 256) U0[(long)(i/12)*512 + 500 + (i%12)] = 0;
            }
        }
    } else if (bi < 496) {
        int sub = bi - 480;
        int oend = sub*625 + 625;
        for (int o = sub*625 + tid; o < oend; o += 256) {
            int r = o / 100, cix = o - (o/100)*100;
            const float* arow = l1w + r*200;
            float acc = 0.f;
            for (int e = 0; e < 200; ++e) acc += arow[e] * l2w[e*100 + cix];
            Mp[r*100 + cix] = acc;
        }
    } else if (bi == 496) {
        if (tid < 100) {
            float acc = l2b[tid];
            for (int e = 0; e < 200; ++e) acc += l1b[e] * l2w[e*100 + tid];
            c0v[tid] = acc;
        }
    } else if (bi < 500) {
        int l = bi - 497;   // per-layer FFN weight transposes
        unsigned short* F1 = f1wT + (long)l*8192;
        for (int i = tid; i < 8192; i += 256) {
            int o = i >> 7, k = i & 127;
            F1[i] = (k < 100) ? f2bf(f1w[l*6400 + k*64 + o]) : (unsigned short)0;
        }
        unsigned short* F2 = f2wT + (long)l*7168;
        for (int i = tid; i < 7168; i += 256) {
            int o2 = i >> 6, k2 = i & 63;
            F2[i] = (o2 < 100) ? f2bf(f2w[l*6400 + k2*100 + o2]) : (unsigned short)0;
        }
    } else if (bi == 500) {
        // adjacency normalization
        __shared__ float adj[1024];
        __shared__ float rs[32];
        for (int i = tid; i < 1024; i += 256) {
            int r = i >> 5, j = i & 31;
            adj[i] = A[i] + (r == j ? 1.f : 0.f);
        }
        __syncthreads();
        if (tid < 32) {
            float s = 0.f;
            #pragma unroll
            for (int jj = 0; jj < 32; ++jj) s += adj[tid*32 + jj];
            rs[tid] = s;
        }
        __syncthreads();
        for (int i = tid; i < 1024; i += 256) adjh[i] = adj[i] / rs[i >> 5];
    } else {
        // GCN weight transposes: gw1T[o:64][k:128], gw2T[o:112][k:64]
        for (int i = tid; i < 8192; i += 256) {
            int o = i >> 7, k = i & 127;
            gw1T[i] = (o < 60 && k < 100) ? f2bf(gw1[k*60 + o]) : (unsigned short)0;
        }
        for (int i = tid; i < 7168; i += 256) {
            int o = i >> 6, k = i & 63;
            gw2T[i] = (o < 100 && k < 60) ? f2bf(gw2[k*100 + o]) : (unsigned short)0;
        }
    }
}

// ---------------- GCN gemm1: g[row][64] bf16 = X @ w1 (wave-private MFMA, 32 rows/block) ----
// X loads vectorized: float4 x2 per ks.
__global__ void __launch_bounds__(128) k_gw1(const float* __restrict__ X,
                                             const unsigned short* __restrict__ gw1T,
                                             unsigned short* __restrict__ g) {
    const int tid = threadIdx.x, wave = tid >> 6, lane = tid & 63;
    const int l15 = lane & 15, l4 = lane >> 4;
    const long row = (long)blockIdx.x*32 + wave*16 + l15;
    const float* xrp = X + row*100;
    float4v acc[4];
    #pragma unroll
    for (int mt = 0; mt < 4; ++mt) acc[mt] = (float4v){0,0,0,0};
    #pragma unroll
    for (int ks = 0; ks < 4; ++ks) {
        const int k0 = ks*32 + l4*8;
        short8 b;
        if (k0 + 8 <= 100) {
            float4 v0 = *(const float4*)(xrp + k0);
            float4 v1 = *(const float4*)(xrp + k0 + 4);
            b[0] = (short)f2bf(v0.x); b[1] = (short)f2bf(v0.y);
            b[2] = (short)f2bf(v0.z); b[3] = (short)f2bf(v0.w);
            b[4] = (short)f2bf(v1.x); b[5] = (short)f2bf(v1.y);
            b[6] = (short)f2bf(v1.z); b[7] = (short)f2bf(v1.w);
        } else if (k0 < 100) {   // k0 == 96: 4 valid
            float4 v0 = *(const float4*)(xrp + k0);
            b[0] = (short)f2bf(v0.x); b[1] = (short)f2bf(v0.y);
            b[2] = (short)f2bf(v0.z); b[3] = (short)f2bf(v0.w);
            b[4] = 0; b[5] = 0; b[6] = 0; b[7] = 0;
        } else {
            #pragma unroll
            for (int e = 0; e < 8; ++e) b[e] = 0;
        }
        #pragma unroll
        for (int mt = 0; mt < 4; ++mt) {
            short8 a = *(const short8*)((const short*)gw1T + (mt*16 + l15)*128 + ks*32 + l4*8);
            acc[mt] = __builtin_amdgcn_mfma_f32_16x16x32_bf16(a, b, acc[mt], 0, 0, 0);
        }
    }
    #pragma unroll
    for (int mt = 0; mt < 4; ++mt) {
        int o0 = mt*16 + l4*4;
        *(uint2v*)(g + row*64 + o0) =
            (uint2v){pk2bf(acc[mt][0], acc[mt][1]), pk2bf(acc[mt][2], acc[mt][3])};
    }
}

// ---------------- GCN spmm1: hid[row][64] bf16 = relu(adjh @ g + b1) ----------------
__global__ void __launch_bounds__(256) k_spmmg(const float* __restrict__ adjh,
                                               const unsigned short* __restrict__ g,
                                               const float* __restrict__ b1,
                                               unsigned short* __restrict__ hid) {
    __shared__ float adj[1024];
    int tid = threadIdx.x;
    for (int i = tid; i < 1024; i += 256) adj[i] = adjh[i];
    __syncthreads();
    long p = (long)blockIdx.x*256 + tid;     // p = t*64 + o, in [0, 49152)
    int o = (int)(p & 63);
    float acc[32];
    #pragma unroll
    for (int i = 0; i < 32; ++i) acc[i] = 0.f;
    for (int j = 0; j < 32; ++j) {
        float xv = bf2f(g[(long)j*49152 + p]);
        #pragma unroll
        for (int i = 0; i < 32; ++i) acc[i] += adj[i*32 + j] * xv;
    }
    float bias = (o < 60) ? b1[o] : 0.f;
    #pragma unroll
    for (int i = 0; i < 32; ++i) hid[(long)i*49152 + p] = f2bf(fmaxf(acc[i] + bias, 0.f));
}

// ---------------- GCN gemm2: h2[row][128] bf16 = hid @ w2 (32 rows/block) ----------------
__global__ void __launch_bounds__(128) k_gw2(const unsigned short* __restrict__ hid,
                                             const unsigned short* __restrict__ gw2T,
                                             unsigned short* __restrict__ h2) {
    const int tid = threadIdx.x, wave = tid >> 6, lane = tid & 63;
    const int l15 = lane & 15, l4 = lane >> 4;
    const long row = (long)blockIdx.x*32 + wave*16 + l15;
    float4v acc[7];
    #pragma unroll
    for (int mt = 0; mt < 7; ++mt) acc[mt] = (float4v){0,0,0,0};
    #pragma unroll
    for (int ks = 0; ks < 2; ++ks) {
        short8 b = *(const short8*)((const short*)hid + row*64 + ks*32 + l4*8);
        #pragma unroll
        for (int mt = 0; mt < 7; ++mt) {
            short8 a = *(const short8*)((const short*)gw2T + (mt*16 + l15)*64 + ks*32 + l4*8);
            acc[mt] = __builtin_amdgcn_mfma_f32_16x16x32_bf16(a, b, acc[mt], 0, 0, 0);
        }
    }
    #pragma unroll
    for (int mt = 0; mt < 7; ++mt) {
        int o0 = mt*16 + l4*4;
        *(uint2v*)(h2 + row*128 + o0) =
            (uint2v){pk2bf(acc[mt][0], acc[mt][1]), pk2bf(acc[mt][2], acc[mt][3])};
    }
    *(uint2v*)(h2 + row*128 + 112 + l4*4) = (uint2v){0u, 0u};
}

// ---------------- GCN spmm2 + prep: x0 fp32, xrow bf16[row][128], xT bf16[c][128][768] ----
// grid 256 x 384 threads; p = t*128 + o over [0, 98304). xT key dim permuted.
__global__ void __launch_bounds__(384) k_spmmx(const float* __restrict__ adjh,
                                               const unsigned short* __restrict__ h2,
                                               const float* __restrict__ b2,
                                               float* __restrict__ x0,
                                               unsigned short* __restrict__ xrow,
                                               unsigned short* __restrict__ xT) {
    __shared__ float adj[1024];
    int tid = threadIdx.x;
    for (int i = tid; i < 1024; i += 384) adj[i] = adjh[i];
    __syncthreads();
    long p = (long)blockIdx.x*384 + tid;     // p = t*128 + o
    int o = (int)(p & 127);
    int t = (int)(p >> 7);
    int tp = permt(t);
    float acc[32];
    #pragma unroll
    for (int i = 0; i < 32; ++i) acc[i] = 0.f;
    for (int j = 0; j < 32; ++j) {
        float xv = bf2f(h2[(long)j*98304 + p]);
        #pragma unroll
        for (int i = 0; i < 32; ++i) acc[i] += adj[i*32 + j] * xv;
    }
    if (o < 100) {
        float bias = b2[o];
        #pragma unroll
        for (int i = 0; i < 32; ++i) {
            float v = acc[i] + bias;
            x0[((long)i*768 + t)*100 + o] = v;
            unsigned short bv = f2bf(v);
            xrow[((long)i*768 + t)*128 + o] = bv;
            xT[(long)i*98304 + (long)o*768 + tp] = bv;
        }
    } else {
        #pragma unroll
        for (int i = 0; i < 32; ++i) {
            xrow[((long)i*768 + t)*128 + o] = 0;
            if (o < 112) xT[(long)i*98304 + (long)o*768 + tp] = 0;
        }
    }
}

// ---------------- fused Q-proj + flash attention, 1 set/wave x 8 waves (R31) ----------------
__global__ void __launch_bounds__(512) k_attn14(const unsigned short* __restrict__ xrow,
                                                const unsigned short* __restrict__ xT,
                                                const unsigned short* __restrict__ MhT,
                                                unsigned short* __restrict__ Wb) {
    __shared__ __align__(16) short xr[2][64 * 128];      // 32768 B; also Q-proj scratch
    __shared__ __align__(16) short xt[112 * 64];         // 14336 B
    const int tid = threadIdx.x;
    const int wave = tid >> 6, lane = tid & 63;
    const int l15 = lane & 15, l4 = lane >> 4;
    const int c = blockIdx.z, h = blockIdx.y, q0 = blockIdx.x * 128;

    const short* xrg = (const short*)xrow + (long)c*768*128;
    const short* xtg = (const short*)xT + (long)c*128*768;
    const int rl4 = lane >> 4, cp16 = lane & 15;
    const int rl8 = lane >> 3, cp8 = lane & 7;
    const int njt = (wave < 7) ? 2 : 0;      // xt staging: waves 0-6 x 16 rows
    const int sw8 = (l15 & 7) << 3;          // myq col swizzle (shorts)
    const int swt = l15 & 7;                 // xt 16B-chunk swizzle

    // ---- fused Q-projection, 1 set/wave (scratch = both xr buffers) ----
    short8 qb[4];
    {
        short* mq = &xr[0][0] + wave * 2048;   // 16 rows x 128 shorts per wave
        const short* Mb = (const short*)MhT + (long)h*16384 + l15*128 + l4*8;
        const short* xq = (const short*)xrow + ((long)c*768 + q0 + wave*16 + l15)*128 + l4*8;
        short8 bq[4];
        #pragma unroll
        for (int kk = 0; kk < 4; ++kk) bq[kk] = *(const short8*)(xq + kk*32);
        float4v qc[8];
        #pragma unroll
        for (int mt = 0; mt < 8; ++mt) qc[mt] = (float4v){0,0,0,0};
        __builtin_amdgcn_s_setprio(1);
        #pragma unroll
        for (int mt = 0; mt < 8; ++mt) {
            #pragma unroll
            for (int kk = 0; kk < 4; ++kk) {
                short8 a = *(const short8*)(Mb + (mt*16)*128 + kk*32);
                qc[mt] = __builtin_amdgcn_mfma_f32_16x16x32_bf16(a, bq[kk], qc[mt], 0, 0, 0);
            }
        }
        __builtin_amdgcn_s_setprio(0);
        #pragma unroll
        for (int mt = 0; mt < 8; ++mt)
            st4s(mq + l15*128 + ((mt*16 + l4*4) ^ sw8),
                 pk2bf(qc[mt][0], qc[mt][1]), pk2bf(qc[mt][2], qc[mt][3]));
        asm volatile("" ::: "memory");
        #pragma unroll
        for (int kk = 0; kk < 4; ++kk)
            qb[kk] = *(const short8*)(mq + l15*128 + ((kk*32 + l4*8) ^ sw8));
        asm volatile("" ::: "memory");
    }

    __syncthreads();   // all scratch reads done block-wide; xr reusable as K tiles

    // stage xr(0) (2 calls/wave x 4 rows = 8 rows/wave, 64 rows total)
    #pragma unroll
    for (int j = 0; j < 2; ++j) {
        int row = wave*8 + j*4 + rl4;
        int lc = cp16 ^ (row & 7);
        gload16(xrg + (long)row*128 + lc*8, xr[0] + (wave*8 + j*4)*128);
    }
    __syncthreads();   // implicit vmcnt(0): xr(0) landed in all waves

    float4v o[7];
    #pragma unroll
    for (int n = 0; n < 7; ++n) o[n] = (float4v){0,0,0,0};
    float lsum = 0.f;

    for (int kt = 0; kt < 12; ++kt) {
        const int key0 = kt * 64;
        const short* xrb = xr[kt & 1];

        // issue xt(kt) FIRST (must land before PV; mid-wait counts on order)
        for (int j = 0; j < njt; ++j) {
            int row = wave*16 + j*8 + rl8;
            int lc = cp8 ^ (row & 7);
            gload16(xtg + (long)row*768 + key0 + lc*8, xt + (wave*16 + j*8)*64);
        }
        // then issue xr(kt+1) into the other buffer (hidden under full kt body)
        if (kt < 11) {
            short* xrn = xr[(kt + 1) & 1];
            #pragma unroll
            for (int j = 0; j < 2; ++j) {
                int row = wave*8 + j*4 + rl4;
                int lc = cp16 ^ (row & 7);
                gload16(xrg + (long)(key0 + 64 + row)*128 + lc*8, xrn + (wave*8 + j*4)*128);
            }
        }
        __builtin_amdgcn_sched_barrier(0);   // pin: staging issues stay above compute

        // ---- QK phase 1: kn = 0,1 -> packed P words (keys kn*16 + l4*4 + r) ----
        unsigned pw[4];
        __builtin_amdgcn_s_setprio(1);
        #pragma unroll
        for (int kn = 0; kn < 2; ++kn) {
            float4v s0 = (float4v){0,0,0,0};
            #pragma unroll
            for (int kk = 0; kk < 4; ++kk) {
                short8 a = *(const short8*)(xrb + (kn*16 + l15)*128 + (((kk*4 + l4) ^ (l15 & 7))*8));
                s0 = __builtin_amdgcn_mfma_f32_16x16x32_bf16(a, qb[kk], s0, 0, 0, 0);
            }
            float p[4];
            #pragma unroll
            for (int r = 0; r < 4; ++r) { p[r] = __expf(s0[r]); lsum += p[r]; }
            pw[kn*2]   = pk2bf(p[0], p[1]); pw[kn*2+1] = pk2bf(p[2], p[3]);
        }
        __builtin_amdgcn_s_setprio(0);

        // wait own xt loads landed (own xr-next 2 stay in flight), then barrier
        if (kt < 11) { asm volatile("s_waitcnt vmcnt(2)" ::: "memory"); }
        else         { asm volatile("s_waitcnt vmcnt(0)" ::: "memory"); }
        __builtin_amdgcn_s_barrier();

        // ---- PV pass A: keys [0,32). b = own packed words; a = one b128 ----
        __builtin_amdgcn_s_setprio(1);
        {
            short8 b0 = __builtin_bit_cast(short8, (uint4v){pw[0], pw[1], pw[2], pw[3]});
            const int offA = ((l4 ^ swt) * 8);
            #pragma unroll
            for (int dt = 0; dt < 7; ++dt) {
                short8 a = *(const short8*)(xt + (dt*16 + l15)*64 + offA);
                o[dt] = __builtin_amdgcn_mfma_f32_16x16x32_bf16(a, b0, o[dt], 0, 0, 0);
            }
        }

        // ---- QK phase 2: kn = 2,3 ----
        unsigned pwb[4];
        #pragma unroll
        for (int kn = 2; kn < 4; ++kn) {
            float4v s0 = (float4v){0,0,0,0};
            #pragma unroll
            for (int kk = 0; kk < 4; ++kk) {
                short8 a = *(const short8*)(xrb + (kn*16 + l15)*128 + (((kk*4 + l4) ^ (l15 & 7))*8));
                s0 = __builtin_amdgcn_mfma_f32_16x16x32_bf16(a, qb[kk], s0, 0, 0, 0);
            }
            float p[4];
            #pragma unroll
            for (int r = 0; r < 4; ++r) { p[r] = __expf(s0[r]); lsum += p[r]; }
            pwb[(kn-2)*2]   = pk2bf(p[0], p[1]); pwb[(kn-2)*2+1] = pk2bf(p[2], p[3]);
        }

        // ---- PV pass B: keys [32,64). a = one b128 at chunk (4+l4)^swt ----
        {
            short8 b0 = __builtin_bit_cast(short8, (uint4v){pwb[0], pwb[1], pwb[2], pwb[3]});
            const int offB = (((4 + l4) ^ swt) * 8);
            #pragma unroll
            for (int dt = 0; dt < 7; ++dt) {
                short8 a = *(const short8*)(xt + (dt*16 + l15)*64 + offB);
                o[dt] = __builtin_amdgcn_mfma_f32_16x16x32_bf16(a, b0, o[dt], 0, 0, 0);
            }
        }
        __builtin_amdgcn_s_setprio(0);
        __syncthreads();   // xr-next landed (had whole body); all xt reads done
    }

    float l0 = lsum;
    l0 += __shfl_xor(l0, 16, 64); l0 += __shfl_xor(l0, 32, 64);
    float inv0 = 1.f / l0;

    unsigned short* Wo = Wb + ((long)(c*768 + q0 + wave*16 + l15))*512 + h*100 + l4*4;
    #pragma unroll
    for (int dt = 0; dt < 7; ++dt) {
        if (dt < 6 || l4 == 0) {
            *(uint2v*)(Wo + dt*16) = (uint2v){pk2bf(o[dt][0]*inv0, o[dt][1]*inv0),
                                              pk2bf(o[dt][2]*inv0, o[dt][3]*inv0)};
        }
    }
    if (h == 0) {
        unsigned short* Wz = Wb + ((long)c*768 + q0)*512 + 500;
        for (int i = tid; i < 1536; i += 512) Wz[(long)(i/12)*512 + (i%12)] = 0;
    }
}

// ---------------- fused encoder tail (32 rows/block, 2 waves), UstT LDS-staged ----
template<bool EMIT>
__global__ void __launch_bounds__(128) k_tail(const unsigned short* __restrict__ Wb,
        const unsigned short* __restrict__ UstT,
        const unsigned short* __restrict__ f1wT, const unsigned short* __restrict__ f2wT,
        const float* __restrict__ f1b, const float* __restrict__ f2b,
        const float* __restrict__ g1, const float* __restrict__ b1,
        const float* __restrict__ g2, const float* __restrict__ b2,
        float* __restrict__ x, unsigned short* __restrict__ xrow, unsigned short* __restrict__ xT) {
    __shared__ __align__(16) short ust[2][128 * 64];   // 2 x 16KB (128 rows x 64 shorts)
    const int tid = threadIdx.x, wave = tid >> 6, lane = tid & 63;
    const int l15 = lane & 15, l4 = lane >> 4;
    const long row = (long)blockIdx.x*32 + wave*16 + l15;
    const int cc = blockIdx.x / 24;
    const int tt = (blockIdx.x % 24)*32 + wave*16 + l15;
    const int ttp = permt(tt);                  // xT key-dim permutation
    const int sr8 = lane >> 3, sc8 = lane & 7;  // staging: 8 rows/call, 8 chunks/row

    const short* Wr = (const short*)Wb + row*512 + l4*8;
    float4v o[8];
    #pragma unroll
    for (int mt = 0; mt < 8; ++mt) o[mt] = (float4v){0,0,0,0};

    // ---- stage chunk 0 ----
    {
        short* dst = ust[0];
        #pragma unroll
        for (int j = 0; j < 8; ++j) {
            int r = wave*64 + j*8 + sr8;
            int lc = sc8 ^ (r & 7);
            gload16((const short*)UstT + (long)r*512 + 0 + lc*8, dst + (wave*64 + j*8)*64);
        }
    }
    __syncthreads();

    short8 bc0 = *(const short8*)(Wr + 0);
    short8 bc1 = *(const short8*)(Wr + 32);
    for (int cb = 0; cb < 8; ++cb) {
        // prefetch next chunk + next b-regs (hidden under this chunk's MFMAs)
        if (cb < 7) {
            const int ksb = (cb + 1) * 64;
            short* dst = ust[(cb + 1) & 1];
            #pragma unroll
            for (int j = 0; j < 8; ++j) {
                int r = wave*64 + j*8 + sr8;
                int lc = sc8 ^ (r & 7);
                gload16((const short*)UstT + (long)r*512 + ksb + lc*8, dst + (wave*64 + j*8)*64);
            }
        }
        short8 bn0, bn1;
        if (cb < 7) {
            bn0 = *(const short8*)(Wr + (cb*2 + 2)*32);
            bn1 = *(const short8*)(Wr + (cb*2 + 3)*32);
        }
        __builtin_amdgcn_sched_barrier(0);

        const short* bufc = ust[cb & 1];
        __builtin_amdgcn_s_setprio(1);
        #pragma unroll
        for (int mt = 0; mt < 8; ++mt) {
            short8 a0 = *(const short8*)(bufc + (mt*16 + l15)*64 + (((0*4 + l4) ^ (l15 & 7))*8));
            o[mt] = __builtin_amdgcn_mfma_f32_16x16x32_bf16(a0, bc0, o[mt], 0, 0, 0);
            short8 a1 = *(const short8*)(bufc + (mt*16 + l15)*64 + (((1*4 + l4) ^ (l15 & 7))*8));
            o[mt] = __builtin_amdgcn_mfma_f32_16x16x32_bf16(a1, bc1, o[mt], 0, 0, 0);
        }
        __builtin_amdgcn_s_setprio(0);
        bc0 = bn0; bc1 = bn1;
        __syncthreads();   // next buf staged in all waves; this buf's reads done
    }

    // overlay scratch into ust buffers (free after the GEMM; barrier above protects)
    short* myz = ust[0] + wave * 2176;   // 16 rows x 136
    short* myt = ust[1] + wave * 1152;   // 16 rows x 72

    float zv[7][4];
    float sum = 0.f;
    #pragma unroll
    for (int mt = 0; mt < 7; ++mt) {
        int f0 = mt*16 + l4*4;
        float4 xv = {0,0,0,0};
        if (f0 < 100) xv = *(const float4*)(x + row*100 + f0);
        #pragma unroll
        for (int r = 0; r < 4; ++r) {
            float z = 0.f;
            if (f0 < 100) { z = o[mt][r] + ((const float*)&xv)[r]; sum += z; }
            zv[mt][r] = z;
        }
    }
    sum += __shfl_xor(sum, 16, 64); sum += __shfl_xor(sum, 32, 64);
    float mean = sum * 0.01f;
    float vs = 0.f;
    #pragma unroll
    for (int mt = 0; mt < 7; ++mt) {
        if (mt*16 + l4*4 < 100) {
            #pragma unroll
            for (int r = 0; r < 4; ++r) { float d = zv[mt][r] - mean; vs += d*d; }
        }
    }
    vs += __shfl_xor(vs, 16, 64); vs += __shfl_xor(vs, 32, 64);
    float inv = rsqrtf(vs * 0.01f + 1e-5f);
    float x1r[7][4];
    #pragma unroll
    for (int mt = 0; mt < 7; ++mt) {
        int f0 = mt*16 + l4*4;
        float4 gv = {0,0,0,0}, bv = {0,0,0,0};
        if (f0 < 100) { gv = *(const float4*)(g1 + f0); bv = *(const float4*)(b1 + f0); }
        #pragma unroll
        for (int r = 0; r < 4; ++r)
            x1r[mt][r] = (f0 < 100) ? (zv[mt][r] - mean) * inv * ((const float*)&gv)[r] + ((const float*)&bv)[r] : 0.f;
    }

    #pragma unroll
    for (int mt = 0; mt < 8; ++mt) {
        float v0 = (mt < 7) ? x1r[mt][0] : 0.f, v1 = (mt < 7) ? x1r[mt][1] : 0.f;
        float v2 = (mt < 7) ? x1r[mt][2] : 0.f, v3 = (mt < 7) ? x1r[mt][3] : 0.f;
        st4s(myz + l15*136 + mt*16 + l4*4, pk2bf(v0, v1), pk2bf(v2, v3));
    }
    asm volatile("" ::: "memory");

    float4v t2[4];
    #pragma unroll
    for (int m2t = 0; m2t < 4; ++m2t) t2[m2t] = (float4v){0,0,0,0};
    #pragma unroll
    for (int ks = 0; ks < 4; ++ks) {
        short8 b = *(const short8*)(myz + l15*136 + ks*32 + l4*8);
        #pragma unroll
        for (int m2t = 0; m2t < 4; ++m2t) {
            short8 a = *(const short8*)((const short*)f1wT + (m2t*16 + l15)*128 + ks*32 + l4*8);
            t2[m2t] = __builtin_amdgcn_mfma_f32_16x16x32_bf16(a, b, t2[m2t], 0, 0, 0);
        }
    }
    #pragma unroll
    for (int m2t = 0; m2t < 4; ++m2t) {
        int m20 = m2t*16 + l4*4;
        float4 bv = *(const float4*)(f1b + m20);
        float v0 = fmaxf(t2[m2t][0] + ((const float*)&bv)[0], 0.f);
        float v1 = fmaxf(t2[m2t][1] + ((const float*)&bv)[1], 0.f);
        float v2 = fmaxf(t2[m2t][2] + ((const float*)&bv)[2], 0.f);
        float v3 = fmaxf(t2[m2t][3] + ((const float*)&bv)[3], 0.f);
        st4s(myt + l15*72 + m20, pk2bf(v0, v1), pk2bf(v2, v3));
    }
    asm volatile("" ::: "memory");

    float4v o3[7];
    #pragma unroll
    for (int m3t = 0; m3t < 7; ++m3t) o3[m3t] = (float4v){0,0,0,0};
    #pragma unroll
    for (int ks2 = 0; ks2 < 2; ++ks2) {
        short8 b = *(const short8*)(myt + l15*72 + ks2*32 + l4*8);
        #pragma unroll
        for (int m3t = 0; m3t < 7; ++m3t) {
            short8 a = *(const short8*)((const short*)f2wT + (m3t*16 + l15)*64 + ks2*32 + l4*8);
            o3[m3t] = __builtin_amdgcn_mfma_f32_16x16x32_bf16(a, b, o3[m3t], 0, 0, 0);
        }
    }

    float z2[7][4];
    float sum2 = 0.f;
    #pragma unroll
    for (int m3t = 0; m3t < 7; ++m3t) {
        int f0 = m3t*16 + l4*4;
        float4 bv = {0,0,0,0};
        if (f0 < 100) bv = *(const float4*)(f2b + f0);
        #pragma unroll
        for (int r = 0; r < 4; ++r) {
            float z = 0.f;
            if (f0 < 100) { z = o3[m3t][r] + ((const float*)&bv)[r] + x1r[m3t][r]; sum2 += z; }
            z2[m3t][r] = z;
        }
    }
    sum2 += __shfl_xor(sum2, 16, 64); sum2 += __shfl_xor(sum2, 32, 64);
    float mean2 = sum2 * 0.01f;
    float vs2 = 0.f;
    #pragma unroll
    for (int m3t = 0; m3t < 7; ++m3t) {
        if (m3t*16 + l4*4 < 100) {
            #pragma unroll
            for (int r = 0; r < 4; ++r) { float d = z2[m3t][r] - mean2; vs2 += d*d; }
        }
    }
    vs2 += __shfl_xor(vs2, 16, 64); vs2 += __shfl_xor(vs2, 32, 64);
    float inv2 = rsqrtf(vs2 * 0.01f + 1e-5f);

    unsigned short* xTc = EMIT ? (xT + (long)cc*98304 + ttp) : nullptr;
    #pragma unroll
    for (int m3t = 0; m3t < 7; ++m3t) {
        int f0 = m3t*16 + l4*4;
        if (f0 < 100) {
            float4 gv = *(const float4*)(g2 + f0);
            float4 bv = *(const float4*)(b2 + f0);
            float y[4];
            #pragma unroll
            for (int r = 0; r < 4; ++r)
                y[r] = (z2[m3t][r] - mean2) * inv2 * ((const float*)&gv)[r] + ((const float*)&bv)[r];
            *(float4*)(x + row*100 + f0) = (float4){y[0], y[1], y[2], y[3]};
            if (EMIT) {
                *(uint2v*)(xrow + row*128 + f0) = (uint2v){pk2bf(y[0], y[1]), pk2bf(y[2], y[3])};
                #pragma unroll
                for (int r = 0; r < 4; ++r)
                    xTc[(long)(f0 + r)*768] = f2bf(y[r]);
            }
        } else if (EMIT) {
            *(uint2v*)(xrow + row*128 + f0) = (uint2v){0u, 0u};
            #pragma unroll
            for (int r = 0; r < 4; ++r)
                if (f0 + r < 112) xTc[(long)(f0 + r)*768] = 0;
        }
    }
    if (EMIT) *(uint2v*)(xrow + row*128 + 112 + l4*4) = (uint2v){0u, 0u};
}

// ---------------- autoregressive predictor (composed linear map) ----------------
__global__ void __launch_bounds__(256) k_pred2(const float* __restrict__ xf,
        const float* __restrict__ Mp, const float* __restrict__ c0v,
        float* __restrict__ out) {
    int c = blockIdx.x, tid = threadIdx.x;
    __shared__ float Ml[10000];
    __shared__ float carry[100];
    for (int i = tid; i < 10000; i += 256) Ml[i] = Mp[i];
    if (tid < 100) carry[tid] = xf[((long)c*768 + 767)*100 + tid];
    __syncthreads();
    for (int s = 0; s < 10; ++s) {
        float pv = 0.f;
        if (tid < 100) {
            pv = c0v[tid];
            for (int d = 0; d < 100; ++d) pv += carry[d] * Ml[d*100 + tid];
            out[((long)c*10 + s)*100 + tid] = pv;
        }
        __syncthreads();
        if (tid < 100) carry[tid] = pv;
        __syncthreads();
    }
}

extern "C" void kernel_launch(void* const* d_in, const int* in_sizes, int n_in,
                              void* d_out, int out_size, void* d_ws, size_t ws_size,
                              hipStream_t stream) {
    const float* X    = (const float*)d_in[0];
    const float* A    = (const float*)d_in[1];
    const float* gw1  = (const float*)d_in[2];
    const float* gb1  = (const float*)d_in[3];
    const float* gw2  = (const float*)d_in[4];
    const float* gb2  = (const float*)d_in[5];
    const float* wq   = (const float*)d_in[6];
    const float* wk   = (const float*)d_in[7];
    const float* wv   = (const float*)d_in[8];
    const float* wm   = (const float*)d_in[9];
    const float* f1w  = (const float*)d_in[10];
    const float* f1b  = (const float*)d_in[11];
    const float* f2w  = (const float*)d_in[12];
    const float* f2b  = (const float*)d_in[13];
    const float* ln1g = (const float*)d_in[14];
    const float* ln1b = (const float*)d_in[15];
    const float* ln2g = (const float*)d_in[16];
    const float* ln2b = (const float*)d_in[17];
    const float* l1w  = (const float*)d_in[18];
    const float* l1b  = (const float*)d_in[19];
    const float* l2w  = (const float*)d_in[20];
    const float* l2b  = (const float*)d_in[21];
    (void)in_sizes; (void)n_in; (void)out_size; (void)ws_size;

    float* ws   = (float*)d_ws;
    float* adjh = ws + OFF_ADJ;
    float* x0   = ws + OFF_X0;
    unsigned short* gbuf = (unsigned short*)(ws + OFF_X1);
    unsigned short* hbuf = (unsigned short*)(ws + OFF_X1 + 786432L);
    unsigned short* h2buf= (unsigned short*)(ws + OFF_X1 + 1572864L);
    unsigned short* xrow = (unsigned short*)(ws + OFF_XROW);
    unsigned short* xTb  = (unsigned short*)(ws + OFF_XT);
    unsigned short* Wbf  = (unsigned short*)(ws + OFF_WBF);
    unsigned short* MhT  = (unsigned short*)(ws + OFF_MHT);
    unsigned short* UstT = (unsigned short*)(ws + OFF_USTT);
    float* Mp   = ws + OFF_MP;
    float* c0v  = ws + OFF_C0;
    unsigned short* f1wT = (unsigned short*)(ws + OFF_F1WT);
    unsigned short* f2wT = (unsigned short*)(ws + OFF_F2WT);
    unsigned short* gw1T = (unsigned short*)(ws + OFF_GW1T);
    unsigned short* gw2T = (unsigned short*)(ws + OFF_GW2T);
    float* out  = (float*)d_out;

    k_mu2<<<502, 256, 0, stream>>>(wq, wk, wv, wm, l1w, l1b, l2w, l2b, f1w, f2w, A, gw1, gw2,
                                   MhT, UstT, Mp, c0v, f1wT, f2wT, adjh, gw1T, gw2T);

    // GCN (MFMA weight-gemms; spmms commuted; last spmm emits xrow/xT directly)
    k_gw1<<<768, 128, 0, stream>>>(X, gw1T, gbuf);
    k_spmmg<<<192, 256, 0, stream>>>(adjh, gbuf, gb1, hbuf);
    k_gw2<<<768, 128, 0, stream>>>(hbuf, gw2T, h2buf);
    k_spmmx<<<256, 384, 0, stream>>>(adjh, h2buf, gb2, x0, xrow, xTb);

    // encoder layers: attn + fused tail
    for (int l = 0; l < 3; ++l) {
        k_attn14<<<dim3(6,5,32), 512, 0, stream>>>(xrow, xTb, MhT + (long)l*81920, Wbf);
        if (l < 2)
            k_tail<true><<<768, 128, 0, stream>>>(Wbf, UstT + (long)l*65536,
                f1wT + (long)l*8192, f2wT + (long)l*7168, f1b + l*64, f2b + l*100,
                ln1g + l*100, ln1b + l*100, ln2g + l*100, ln2b + l*100, x0, xrow, xTb);
        else
            k_tail<false><<<768, 128, 0, stream>>>(Wbf, UstT + (long)l*65536,
                f1wT + (long)l*8192, f2wT + (long)l*7168, f1b + l*64, f2b + l*100,
                ln1g + l*100, ln1b + l*100, ln2g + l*100, ln2b + l*100, x0, xrow, xTb);
    }

    k_pred2<<<32, 256, 0, stream>>>(x0, Mp, c0v, out);
}

// Round 18
// 459.281 us; speedup vs baseline: 1.0787x; 1.0787x over previous
//
#include <hip/hip_runtime.h>

// GTA model: GCN(2-hop) -> 3x transformer encoder -> 10-step AR predictor.
// R32 (final): revert to R28/R30 exactly (twice-verified best: 461.2us,
// absmax 0.0039). R31's 1-set/8-wave occupancy play falsified: occupancy
// doubled (36.6%) but attn regressed 80.7->91us (halved b-reuse doubled LDS
// traffic + per-wave overhead; MfmaUtil fell to 21.5). attn12's design point
// is now measurement-bracketed in every direction (4-set: regs; 1-set: LDS;
// fewer barriers: races; no staging: latency). Session: 531.3 -> 461.2us.
// Kernel set: attn12 (zero-shuffle PV, permuted xT, xr-dbuf + vmcnt(4)
// pipeline, setprio), k_tail (UstT LDS-staged dbuf), vectorized gw1/mu2.

#define ROWS 24576   // C*T = 32*768

// workspace offsets (floats)
#define OFF_ADJ   0L
#define OFF_X0    1024L
#define OFF_X1    (OFF_X0 + 2457600L)
#define OFF_XROW  (OFF_X1 + 3932160L)        // 24576*128 bf16 = 1572864 floats
#define OFF_XT    (OFF_XROW + 1572864L)
#define OFF_WBF   (OFF_XT + 1572864L)        // 24576*512 bf16 = 6291456 floats
#define OFF_MHT   (OFF_WBF + 6291456L)       // 15*128*128 bf16 = 122880 floats
#define OFF_USTT  (OFF_MHT + 122880L)        // 3*128*512 bf16 = 98304 floats
#define OFF_MP    (OFF_USTT + 98304L)        // 100*100 fp32
#define OFF_C0    (OFF_MP + 10000L)          // 100 fp32 (pad to 128)
#define OFF_F1WT  (OFF_C0 + 128L)            // 3*64*128 bf16 = 12288 floats
#define OFF_F2WT  (OFF_F1WT + 12288L)        // 3*112*64 bf16 = 10752 floats
#define OFF_GW1T  (OFF_F2WT + 10752L)        // 64*128 bf16 = 4096 floats
#define OFF_GW2T  (OFF_GW1T + 4096L)         // 112*64 bf16 = 3584 floats
// GCN scratch inside OFF_X1 region:
//   g   bf16 24576*64  @ OFF_X1 ; hid bf16 24576*64 @ +786432 ; h2 bf16 24576*128 @ +1572864

typedef __attribute__((ext_vector_type(8))) short short8;
typedef __attribute__((ext_vector_type(4))) short short4v;
typedef __attribute__((ext_vector_type(4))) float float4v;
typedef __attribute__((ext_vector_type(2))) unsigned int uint2v;
typedef __attribute__((ext_vector_type(4))) unsigned int uint4v;

__device__ inline unsigned short f2bf(float f) {
    unsigned u = __builtin_bit_cast(unsigned, f);
    return (unsigned short)((u + 0x7fffu + ((u >> 16) & 1u)) >> 16);
}
// packed f32x2 -> bf16x2, RNE — single v_cvt_pk_bf16_f32.
__device__ inline unsigned pk2bf(float lo, float hi) {
    unsigned r;
    asm("v_cvt_pk_bf16_f32 %0, %1, %2" : "=v"(r) : "v"(lo), "v"(hi));
    return r;
}
// LDS store of 2 packed bf16x2 words, short-typed (TBAA-consistent with loads).
__device__ inline void st4s(short* p, unsigned a, unsigned b) {
    *(short4v*)p = __builtin_bit_cast(short4v, (uint2v){a, b});
}
__device__ inline float bf2f(unsigned short v) {
    return __builtin_bit_cast(float, ((unsigned)v) << 16);
}
// async global->LDS DMA, 16B per lane; LDS dest = wave-uniform base + lane*16
__device__ inline void gload16(const short* g, short* l) {
    __builtin_amdgcn_global_load_lds((const __attribute__((address_space(1))) void*)g,
                                     (__attribute__((address_space(3))) void*)l, 16, 0, 0);
}
// xT key-dim permutation: within each 64-key block, quad q -> slot
// (q&8)|((q&3)<<1)|((q>>2)&1); chunk j then holds quads (j, 4+j).
__device__ inline int permt(int t) {
    int tl = t & 63, q = tl >> 2, r = tl & 3;
    int pos = (q & 8) | ((q & 3) << 1) | ((q >> 2) & 1);
    return (t & ~63) | (pos << 2) | r;
}

// ---------------- precompute: MhT, UstT, f1wT, f2wT, gw1T, gw2T (bf16 padded), Mpred, c0, adjh ----
__global__ void __launch_bounds__(256) k_mu2(const float* __restrict__ wq, const float* __restrict__ wk,
                                             const float* __restrict__ wv, const float* __restrict__ wm,
                                             const float* __restrict__ l1w, const float* __restrict__ l1b,
                                             const float* __restrict__ l2w, const float* __restrict__ l2b,
                                             const float* __restrict__ f1w, const float* __restrict__ f2w,
                                             const float* __restrict__ A,
                                             const float* __restrict__ gw1, const float* __restrict__ gw2,
                                             unsigned short* __restrict__ MhT, unsigned short* __restrict__ UstT,
                                             float* __restrict__ Mp, float* __restrict__ c0v,
                                             unsigned short* __restrict__ f1wT, unsigned short* __restrict__ f2wT,
                                             float* __restrict__ adjh,
                                             unsigned short* __restrict__ gw1T, unsigned short* __restrict__ gw2T) {
    int bi = blockIdx.x, tid = threadIdx.x;
    if (bi < 480) {
        int mat = bi >> 4, sub = bi & 15;
        int mode = mat / 15, idx = mat % 15, l = idx / 5, h = idx % 5;
        const float* Asrc = (mode == 0 ? wq : wv) + (l*5 + h)*10000;
        const float* Bsrc = (mode == 0) ? (wk + (l*5 + h)*10000) : (wm + l*50000 + h*10000);
        int oend = sub*625 + 625;
        for (int o = sub*625 + tid; o < oend; o += 256) {
            int r = o / 100, cix = o - (o/100)*100;
            const float* arow = Asrc + r*100;
            float acc = 0.f;
            if (mode == 0) {
                const float* brow = Bsrc + cix*100;
                float4 s = {0,0,0,0};
                #pragma unroll 5
                for (int e4 = 0; e4 < 25; ++e4) {
                    float4 av = *(const float4*)(arow + e4*4);
                    float4 bv = *(const float4*)(brow + e4*4);
                    s.x += av.x*bv.x; s.y += av.y*bv.y;
                    s.z += av.z*bv.z; s.w += av.w*bv.w;
                }
                acc = (s.x + s.y) + (s.z + s.w);
                MhT[(long)(l*5 + h)*16384 + cix*128 + r] = f2bf(acc * 0.1f);
            } else {
                for (int e = 0; e < 100; ++e) acc += arow[e] * Bsrc[e*100 + cix];
                UstT[(long)l*65536 + (long)cix*512 + h*100 + r] = f2bf(acc);
            }
        }
        if (sub == 0) {   // zero padding
            if (mode == 0) {
                unsigned short* M0 = MhT + (long)(l*5 + h)*16384;
                for (int i = tid; i < 28*128; i += 256) M0[(100 + i/128)*128 + (i%128)] = 0;
                for (int i = tid; i < 100*28; i += 256) M0[(i/28)*128 + 100 + (i%28)] = 0;
            } else if (h == 4) {
                unsigned short* U0 = UstT + (long)l*65536;
                for (int i = tid; i < 28*512; i += 256) U0[(long)(100 + i/512)*512 + (i%512)] = 0;
                for (int i = tid; i < 100*12; i += 256) U0[(long)(i/12)*512 + 500 + (i%12)] = 0;
            }
        }
    } else if (bi < 496) {
        int sub = bi - 480;
        int oend = sub*625 + 625;
        for (int o = sub*625 + tid; o < oend; o += 256) {
            int r = o / 100, cix = o - (o/100)*100;
            const float* arow = l1w + r*200;
            float acc = 0.f;
            for (int e = 0; e < 200; ++e) acc += arow[e] * l2w[e*100 + cix];
            Mp[r*100 + cix] = acc;
        }
    } else if (bi == 496) {
        if (tid < 100) {
            float acc = l2b[tid];
            for (int e = 0; e < 200; ++e) acc += l1b[e] * l2w[e*100 + tid];
            c0v[tid] = acc;
        }
    } else if (bi < 500) {
        int l = bi - 497;   // per-layer FFN weight transposes
        unsigned short* F1 = f1wT + (long)l*8192;
        for (int i = tid; i < 8192; i += 256) {
            int o = i >> 7, k = i & 127;
            F1[i] = (k < 100) ? f2bf(f1w[l*6400 + k*64 + o]) : (unsigned short)0;
        }
        unsigned short* F2 = f2wT + (long)l*7168;
        for (int i = tid; i < 7168; i += 256) {
            int o2 = i >> 6, k2 = i & 63;
            F2[i] = (o2 < 100) ? f2bf(f2w[l*6400 + k2*100 + o2]) : (unsigned short)0;
        }
    } else if (bi == 500) {
        // adjacency normalization
        __shared__ float adj[1024];
        __shared__ float rs[32];
        for (int i = tid; i < 1024; i += 256) {
            int r = i >> 5, j = i & 31;
            adj[i] = A[i] + (r == j ? 1.f : 0.f);
        }
        __syncthreads();
        if (tid < 32) {
            float s = 0.f;
            #pragma unroll
            for (int jj = 0; jj < 32; ++jj) s += adj[tid*32 + jj];
            rs[tid] = s;
        }
        __syncthreads();
        for (int i = tid; i < 1024; i += 256) adjh[i] = adj[i] / rs[i >> 5];
    } else {
        // GCN weight transposes: gw1T[o:64][k:128], gw2T[o:112][k:64]
        for (int i = tid; i < 8192; i += 256) {
            int o = i >> 7, k = i & 127;
            gw1T[i] = (o < 60 && k < 100) ? f2bf(gw1[k*60 + o]) : (unsigned short)0;
        }
        for (int i = tid; i < 7168; i += 256) {
            int o = i >> 6, k = i & 63;
            gw2T[i] = (o < 100 && k < 60) ? f2bf(gw2[k*100 + o]) : (unsigned short)0;
        }
    }
}

// ---------------- GCN gemm1: g[row][64] bf16 = X @ w1 (wave-private MFMA, 32 rows/block) ----
// X loads vectorized: float4 x2 per ks.
__global__ void __launch_bounds__(128) k_gw1(const float* __restrict__ X,
                                             const unsigned short* __restrict__ gw1T,
                                             unsigned short* __restrict__ g) {
    const int tid = threadIdx.x, wave = tid >> 6, lane = tid & 63;
    const int l15 = lane & 15, l4 = lane >> 4;
    const long row = (long)blockIdx.x*32 + wave*16 + l15;
    const float* xrp = X + row*100;
    float4v acc[4];
    #pragma unroll
    for (int mt = 0; mt < 4; ++mt) acc[mt] = (float4v){0,0,0,0};
    #pragma unroll
    for (int ks = 0; ks < 4; ++ks) {
        const int k0 = ks*32 + l4*8;
        short8 b;
        if (k0 + 8 <= 100) {
            float4 v0 = *(const float4*)(xrp + k0);
            float4 v1 = *(const float4*)(xrp + k0 + 4);
            b[0] = (short)f2bf(v0.x); b[1] = (short)f2bf(v0.y);
            b[2] = (short)f2bf(v0.z); b[3] = (short)f2bf(v0.w);
            b[4] = (short)f2bf(v1.x); b[5] = (short)f2bf(v1.y);
            b[6] = (short)f2bf(v1.z); b[7] = (short)f2bf(v1.w);
        } else if (k0 < 100) {   // k0 == 96: 4 valid
            float4 v0 = *(const float4*)(xrp + k0);
            b[0] = (short)f2bf(v0.x); b[1] = (short)f2bf(v0.y);
            b[2] = (short)f2bf(v0.z); b[3] = (short)f2bf(v0.w);
            b[4] = 0; b[5] = 0; b[6] = 0; b[7] = 0;
        } else {
            #pragma unroll
            for (int e = 0; e < 8; ++e) b[e] = 0;
        }
        #pragma unroll
        for (int mt = 0; mt < 4; ++mt) {
            short8 a = *(const short8*)((const short*)gw1T + (mt*16 + l15)*128 + ks*32 + l4*8);
            acc[mt] = __builtin_amdgcn_mfma_f32_16x16x32_bf16(a, b, acc[mt], 0, 0, 0);
        }
    }
    #pragma unroll
    for (int mt = 0; mt < 4; ++mt) {
        int o0 = mt*16 + l4*4;
        *(uint2v*)(g + row*64 + o0) =
            (uint2v){pk2bf(acc[mt][0], acc[mt][1]), pk2bf(acc[mt][2], acc[mt][3])};
    }
}

// ---------------- GCN spmm1: hid[row][64] bf16 = relu(adjh @ g + b1) ----------------
__global__ void __launch_bounds__(256) k_spmmg(const float* __restrict__ adjh,
                                               const unsigned short* __restrict__ g,
                                               const float* __restrict__ b1,
                                               unsigned short* __restrict__ hid) {
    __shared__ float adj[1024];
    int tid = threadIdx.x;
    for (int i = tid; i < 1024; i += 256) adj[i] = adjh[i];
    __syncthreads();
    long p = (long)blockIdx.x*256 + tid;     // p = t*64 + o, in [0, 49152)
    int o = (int)(p & 63);
    float acc[32];
    #pragma unroll
    for (int i = 0; i < 32; ++i) acc[i] = 0.f;
    for (int j = 0; j < 32; ++j) {
        float xv = bf2f(g[(long)j*49152 + p]);
        #pragma unroll
        for (int i = 0; i < 32; ++i) acc[i] += adj[i*32 + j] * xv;
    }
    float bias = (o < 60) ? b1[o] : 0.f;
    #pragma unroll
    for (int i = 0; i < 32; ++i) hid[(long)i*49152 + p] = f2bf(fmaxf(acc[i] + bias, 0.f));
}

// ---------------- GCN gemm2: h2[row][128] bf16 = hid @ w2 (32 rows/block) ----------------
__global__ void __launch_bounds__(128) k_gw2(const unsigned short* __restrict__ hid,
                                             const unsigned short* __restrict__ gw2T,
                                             unsigned short* __restrict__ h2) {
    const int tid = threadIdx.x, wave = tid >> 6, lane = tid & 63;
    const int l15 = lane & 15, l4 = lane >> 4;
    const long row = (long)blockIdx.x*32 + wave*16 + l15;
    float4v acc[7];
    #pragma unroll
    for (int mt = 0; mt < 7; ++mt) acc[mt] = (float4v){0,0,0,0};
    #pragma unroll
    for (int ks = 0; ks < 2; ++ks) {
        short8 b = *(const short8*)((const short*)hid + row*64 + ks*32 + l4*8);
        #pragma unroll
        for (int mt = 0; mt < 7; ++mt) {
            short8 a = *(const short8*)((const short*)gw2T + (mt*16 + l15)*64 + ks*32 + l4*8);
            acc[mt] = __builtin_amdgcn_mfma_f32_16x16x32_bf16(a, b, acc[mt], 0, 0, 0);
        }
    }
    #pragma unroll
    for (int mt = 0; mt < 7; ++mt) {
        int o0 = mt*16 + l4*4;
        *(uint2v*)(h2 + row*128 + o0) =
            (uint2v){pk2bf(acc[mt][0], acc[mt][1]), pk2bf(acc[mt][2], acc[mt][3])};
    }
    *(uint2v*)(h2 + row*128 + 112 + l4*4) = (uint2v){0u, 0u};
}

// ---------------- GCN spmm2 + prep: x0 fp32, xrow bf16[row][128], xT bf16[c][128][768] ----
// grid 256 x 384 threads; p = t*128 + o over [0, 98304). xT key dim permuted.
__global__ void __launch_bounds__(384) k_spmmx(const float* __restrict__ adjh,
                                               const unsigned short* __restrict__ h2,
                                               const float* __restrict__ b2,
                                               float* __restrict__ x0,
                                               unsigned short* __restrict__ xrow,
                                               unsigned short* __restrict__ xT) {
    __shared__ float adj[1024];
    int tid = threadIdx.x;
    for (int i = tid; i < 1024; i += 384) adj[i] = adjh[i];
    __syncthreads();
    long p = (long)blockIdx.x*384 + tid;     // p = t*128 + o
    int o = (int)(p & 127);
    int t = (int)(p >> 7);
    int tp = permt(t);
    float acc[32];
    #pragma unroll
    for (int i = 0; i < 32; ++i) acc[i] = 0.f;
    for (int j = 0; j < 32; ++j) {
        float xv = bf2f(h2[(long)j*98304 + p]);
        #pragma unroll
        for (int i = 0; i < 32; ++i) acc[i] += adj[i*32 + j] * xv;
    }
    if (o < 100) {
        float bias = b2[o];
        #pragma unroll
        for (int i = 0; i < 32; ++i) {
            float v = acc[i] + bias;
            x0[((long)i*768 + t)*100 + o] = v;
            unsigned short bv = f2bf(v);
            xrow[((long)i*768 + t)*128 + o] = bv;
            xT[(long)i*98304 + (long)o*768 + tp] = bv;
        }
    } else {
        #pragma unroll
        for (int i = 0; i < 32; ++i) {
            xrow[((long)i*768 + t)*128 + o] = 0;
            if (o < 112) xT[(long)i*98304 + (long)o*768 + tp] = 0;
        }
    }
}

// ---------------- fused Q-proj + flash attention, zero-shuffle PV, permuted xT ----------------
__global__ void __launch_bounds__(256, 4) k_attn12(const unsigned short* __restrict__ xrow,
                                                   const unsigned short* __restrict__ xT,
                                                   const unsigned short* __restrict__ MhT,
                                                   unsigned short* __restrict__ Wb) {
    __shared__ __align__(16) short xr[2][64 * 128];      // 32768 B, double-buffered keys
    __shared__ __align__(16) short xt[112 * 64];         // 14336 B
    const int tid = threadIdx.x;
    const int wave = tid >> 6, lane = tid & 63;
    const int l15 = lane & 15, l4 = lane >> 4;
    const int c = blockIdx.z, h = blockIdx.y, q0 = blockIdx.x * 128;

    const short* xrg = (const short*)xrow + (long)c*768*128;
    const short* xtg = (const short*)xT + (long)c*128*768;
    const int rl4 = lane >> 4, cp16 = lane & 15;
    const int rl8 = lane >> 3, cp8 = lane & 7;
    const int njt = (wave == 3) ? 2 : 4;
    const int sw8 = (l15 & 7) << 3;          // myq col swizzle (shorts)
    const int swt = l15 & 7;                 // xt 16B-chunk swizzle

    // prefetch xr tile for kt=0 (latency hidden under Q-projection MFMAs)
    #pragma unroll
    for (int j = 0; j < 4; ++j) {
        int row = wave*16 + j*4 + rl4;
        int lc = cp16 ^ (row & 7);
        gload16(xrg + (long)row*128 + lc*8, xr[0] + (wave*16 + j*4)*128);
    }

    // ---- fused Q-projection (myq scratch = xr[1], free until kt=0 staging) ----
    short8 qb0[4], qb1[4];
    {
        short* mq = &xr[1][wave * 16 * 128];   // 16 rows x 128 shorts, swizzled
        const short* Mb = (const short*)MhT + (long)h*16384 + l15*128 + l4*8;
        const short* xq = (const short*)xrow + ((long)c*768 + q0 + wave*16 + l15)*128 + l4*8;
        short8 bq0[4], bq1[4];
        #pragma unroll
        for (int kk = 0; kk < 4; ++kk) {
            bq0[kk] = *(const short8*)(xq + kk*32);
            bq1[kk] = *(const short8*)(xq + 64*128 + kk*32);
        }
        float4v qc0[8], qc1[8];
        #pragma unroll
        for (int mt = 0; mt < 8; ++mt) { qc0[mt] = (float4v){0,0,0,0}; qc1[mt] = (float4v){0,0,0,0}; }
        __builtin_amdgcn_s_setprio(1);
        #pragma unroll
        for (int mt = 0; mt < 8; ++mt) {
            #pragma unroll
            for (int kk = 0; kk < 4; ++kk) {
                short8 a = *(const short8*)(Mb + (mt*16)*128 + kk*32);
                qc0[mt] = __builtin_amdgcn_mfma_f32_16x16x32_bf16(a, bq0[kk], qc0[mt], 0, 0, 0);
                qc1[mt] = __builtin_amdgcn_mfma_f32_16x16x32_bf16(a, bq1[kk], qc1[mt], 0, 0, 0);
            }
        }
        __builtin_amdgcn_s_setprio(0);
        #pragma unroll
        for (int mt = 0; mt < 8; ++mt)
            st4s(mq + l15*128 + ((mt*16 + l4*4) ^ sw8),
                 pk2bf(qc0[mt][0], qc0[mt][1]), pk2bf(qc0[mt][2], qc0[mt][3]));
        asm volatile("" ::: "memory");
        #pragma unroll
        for (int kk = 0; kk < 4; ++kk)
            qb0[kk] = *(const short8*)(mq + l15*128 + ((kk*32 + l4*8) ^ sw8));
        asm volatile("" ::: "memory");
        #pragma unroll
        for (int mt = 0; mt < 8; ++mt)
            st4s(mq + l15*128 + ((mt*16 + l4*4) ^ sw8),
                 pk2bf(qc1[mt][0], qc1[mt][1]), pk2bf(qc1[mt][2], qc1[mt][3]));
        asm volatile("" ::: "memory");
        #pragma unroll
        for (int kk = 0; kk < 4; ++kk)
            qb1[kk] = *(const short8*)(mq + l15*128 + ((kk*32 + l4*8) ^ sw8));
    }

    __syncthreads();   // xr(0) landed; all Q-proj reads of xr[1] done in all waves

    float4v o0[7], o1[7];
    #pragma unroll
    for (int n = 0; n < 7; ++n) { o0[n] = (float4v){0,0,0,0}; o1[n] = (float4v){0,0,0,0}; }
    float lsum0 = 0.f, lsum1 = 0.f;

    for (int kt = 0; kt < 12; ++kt) {
        const int key0 = kt * 64;
        const short* xrb = xr[kt & 1];

        // issue xt(kt) FIRST (must land before PV; mid-wait counts on order)
        for (int j = 0; j < njt; ++j) {
            int row = wave*32 + j*8 + rl8;
            int lc = cp8 ^ (row & 7);
            gload16(xtg + (long)row*768 + key0 + lc*8, xt + (wave*32 + j*8)*64);
        }
        // then issue xr(kt+1) into the other buffer (hidden under full kt body)
        if (kt < 11) {
            short* xrn = xr[(kt + 1) & 1];
            #pragma unroll
            for (int j = 0; j < 4; ++j) {
                int row = wave*16 + j*4 + rl4;
                int lc = cp16 ^ (row & 7);
                gload16(xrg + (long)(key0 + 64 + row)*128 + lc*8, xrn + (wave*16 + j*4)*128);
            }
        }
        __builtin_amdgcn_sched_barrier(0);   // pin: staging issues stay above compute

        // ---- QK phase 1: kn = 0,1 -> packed P words (keys kn*16 + l4*4 + r) ----
        unsigned pw0[4], pw1[4];   // [kn*2 + word] for sets 0/1
        __builtin_amdgcn_s_setprio(1);
        #pragma unroll
        for (int kn = 0; kn < 2; ++kn) {
            float4v s0 = (float4v){0,0,0,0}, s1 = (float4v){0,0,0,0};
            #pragma unroll
            for (int kk = 0; kk < 4; ++kk) {
                short8 a = *(const short8*)(xrb + (kn*16 + l15)*128 + (((kk*4 + l4) ^ (l15 & 7))*8));
                s0 = __builtin_amdgcn_mfma_f32_16x16x32_bf16(a, qb0[kk], s0, 0, 0, 0);
                s1 = __builtin_amdgcn_mfma_f32_16x16x32_bf16(a, qb1[kk], s1, 0, 0, 0);
            }
            float p0[4], p1[4];
            #pragma unroll
            for (int r = 0; r < 4; ++r) {
                p0[r] = __expf(s0[r]); lsum0 += p0[r];
                p1[r] = __expf(s1[r]); lsum1 += p1[r];
            }
            pw0[kn*2]   = pk2bf(p0[0], p0[1]); pw0[kn*2+1] = pk2bf(p0[2], p0[3]);
            pw1[kn*2]   = pk2bf(p1[0], p1[1]); pw1[kn*2+1] = pk2bf(p1[2], p1[3]);
        }
        __builtin_amdgcn_s_setprio(0);

        // wait own xt loads landed (xr-next 4 stay in flight), then barrier
        if (kt < 11) { asm volatile("s_waitcnt vmcnt(4)" ::: "memory"); }
        else         { asm volatile("s_waitcnt vmcnt(0)" ::: "memory"); }
        __builtin_amdgcn_s_barrier();

        // ---- PV pass A: keys [0,32). b = own packed words; a = one b128 ----
        __builtin_amdgcn_s_setprio(1);
        {
            short8 b0 = __builtin_bit_cast(short8, (uint4v){pw0[0], pw0[1], pw0[2], pw0[3]});
            short8 b1 = __builtin_bit_cast(short8, (uint4v){pw1[0], pw1[1], pw1[2], pw1[3]});
            const int offA = ((l4 ^ swt) * 8);
            #pragma unroll
            for (int dt = 0; dt < 7; ++dt) {
                short8 a = *(const short8*)(xt + (dt*16 + l15)*64 + offA);
                o0[dt] = __builtin_amdgcn_mfma_f32_16x16x32_bf16(a, b0, o0[dt], 0, 0, 0);
                o1[dt] = __builtin_amdgcn_mfma_f32_16x16x32_bf16(a, b1, o1[dt], 0, 0, 0);
            }
        }

        // ---- QK phase 2: kn = 2,3 ----
        unsigned pw0b[4], pw1b[4];
        #pragma unroll
        for (int kn = 2; kn < 4; ++kn) {
            float4v s0 = (float4v){0,0,0,0}, s1 = (float4v){0,0,0,0};
            #pragma unroll
            for (int kk = 0; kk < 4; ++kk) {
                short8 a = *(const short8*)(xrb + (kn*16 + l15)*128 + (((kk*4 + l4) ^ (l15 & 7))*8));
                s0 = __builtin_amdgcn_mfma_f32_16x16x32_bf16(a, qb0[kk], s0, 0, 0, 0);
                s1 = __builtin_amdgcn_mfma_f32_16x16x32_bf16(a, qb1[kk], s1, 0, 0, 0);
            }
            float p0[4], p1[4];
            #pragma unroll
            for (int r = 0; r < 4; ++r) {
                p0[r] = __expf(s0[r]); lsum0 += p0[r];
                p1[r] = __expf(s1[r]); lsum1 += p1[r];
            }
            pw0b[(kn-2)*2]   = pk2bf(p0[0], p0[1]); pw0b[(kn-2)*2+1] = pk2bf(p0[2], p0[3]);
            pw1b[(kn-2)*2]   = pk2bf(p1[0], p1[1]); pw1b[(kn-2)*2+1] = pk2bf(p1[2], p1[3]);
        }

        // ---- PV pass B: keys [32,64). a = one b128 at chunk (4+l4)^swt ----
        {
            short8 b0 = __builtin_bit_cast(short8, (uint4v){pw0b[0], pw0b[1], pw0b[2], pw0b[3]});
            short8 b1 = __builtin_bit_cast(short8, (uint4v){pw1b[0], pw1b[1], pw1b[2], pw1b[3]});
            const int offB = (((4 + l4) ^ swt) * 8);
            #pragma unroll
            for (int dt = 0; dt < 7; ++dt) {
                short8 a = *(const short8*)(xt + (dt*16 + l15)*64 + offB);
                o0[dt] = __builtin_amdgcn_mfma_f32_16x16x32_bf16(a, b0, o0[dt], 0, 0, 0);
                o1[dt] = __builtin_amdgcn_mfma_f32_16x16x32_bf16(a, b1, o1[dt], 0, 0, 0);
            }
        }
        __builtin_amdgcn_s_setprio(0);
        __syncthreads();   // xr-next landed (had whole body); all xt reads done
    }

    float l0 = lsum0, l1 = lsum1;
    l0 += __shfl_xor(l0, 16, 64); l0 += __shfl_xor(l0, 32, 64);
    l1 += __shfl_xor(l1, 16, 64); l1 += __shfl_xor(l1, 32, 64);
    float inv0 = 1.f / l0, inv1 = 1.f / l1;

    unsigned short* Wo0 = Wb + ((long)(c*768 + q0 + wave*16 + l15))*512 + h*100 + l4*4;
    unsigned short* Wo1 = Wo0 + 64*512;
    #pragma unroll
    for (int dt = 0; dt < 7; ++dt) {
        if (dt < 6 || l4 == 0) {
            *(uint2v*)(Wo0 + dt*16) = (uint2v){pk2bf(o0[dt][0]*inv0, o0[dt][1]*inv0),
                                               pk2bf(o0[dt][2]*inv0, o0[dt][3]*inv0)};
            *(uint2v*)(Wo1 + dt*16) = (uint2v){pk2bf(o1[dt][0]*inv1, o1[dt][1]*inv1),
                                               pk2bf(o1[dt][2]*inv1, o1[dt][3]*inv1)};
        }
    }
    if (h == 0) {
        unsigned short* Wz = Wb + ((long)c*768 + q0)*512 + 500;
        for (int i = tid; i < 1536; i += 256) Wz[(long)(i/12)*512 + (i%12)] = 0;
    }
}

// ---------------- fused encoder tail (32 rows/block, 2 waves), UstT LDS-staged ----
template<bool EMIT>
__global__ void __launch_bounds__(128) k_tail(const unsigned short* __restrict__ Wb,
        const unsigned short* __restrict__ UstT,
        const unsigned short* __restrict__ f1wT, const unsigned short* __restrict__ f2wT,
        const float* __restrict__ f1b, const float* __restrict__ f2b,
        const float* __restrict__ g1, const float* __restrict__ b1,
        const float* __restrict__ g2, const float* __restrict__ b2,
        float* __restrict__ x, unsigned short* __restrict__ xrow, unsigned short* __restrict__ xT) {
    __shared__ __align__(16) short ust[2][128 * 64];   // 2 x 16KB (128 rows x 64 shorts)
    const int tid = threadIdx.x, wave = tid >> 6, lane = tid & 63;
    const int l15 = lane & 15, l4 = lane >> 4;
    const long row = (long)blockIdx.x*32 + wave*16 + l15;
    const int cc = blockIdx.x / 24;
    const int tt = (blockIdx.x % 24)*32 + wave*16 + l15;
    const int ttp = permt(tt);                  // xT key-dim permutation
    const int sr8 = lane >> 3, sc8 = lane & 7;  // staging: 8 rows/call, 8 chunks/row

    const short* Wr = (const short*)Wb + row*512 + l4*8;
    float4v o[8];
    #pragma unroll
    for (int mt = 0; mt < 8; ++mt) o[mt] = (float4v){0,0,0,0};

    // ---- stage chunk 0 ----
    {
        short* dst = ust[0];
        #pragma unroll
        for (int j = 0; j < 8; ++j) {
            int r = wave*64 + j*8 + sr8;
            int lc = sc8 ^ (r & 7);
            gload16((const short*)UstT + (long)r*512 + 0 + lc*8, dst + (wave*64 + j*8)*64);
        }
    }
    __syncthreads();

    short8 bc0 = *(const short8*)(Wr + 0);
    short8 bc1 = *(const short8*)(Wr + 32);
    for (int cb = 0; cb < 8; ++cb) {
        // prefetch next chunk + next b-regs (hidden under this chunk's MFMAs)
        if (cb < 7) {
            const int ksb = (cb + 1) * 64;
            short* dst = ust[(cb + 1) & 1];
            #pragma unroll
            for (int j = 0; j < 8; ++j) {
                int r = wave*64 + j*8 + sr8;
                int lc = sc8 ^ (r & 7);
                gload16((const short*)UstT + (long)r*512 + ksb + lc*8, dst + (wave*64 + j*8)*64);
            }
        }
        short8 bn0, bn1;
        if (cb < 7) {
            bn0 = *(const short8*)(Wr + (cb*2 + 2)*32);
            bn1 = *(const short8*)(Wr + (cb*2 + 3)*32);
        }
        __builtin_amdgcn_sched_barrier(0);

        const short* bufc = ust[cb & 1];
        __builtin_amdgcn_s_setprio(1);
        #pragma unroll
        for (int mt = 0; mt < 8; ++mt) {
            short8 a0 = *(const short8*)(bufc + (mt*16 + l15)*64 + (((0*4 + l4) ^ (l15 & 7))*8));
            o[mt] = __builtin_amdgcn_mfma_f32_16x16x32_bf16(a0, bc0, o[mt], 0, 0, 0);
            short8 a1 = *(const short8*)(bufc + (mt*16 + l15)*64 + (((1*4 + l4) ^ (l15 & 7))*8));
            o[mt] = __builtin_amdgcn_mfma_f32_16x16x32_bf16(a1, bc1, o[mt], 0, 0, 0);
        }
        __builtin_amdgcn_s_setprio(0);
        bc0 = bn0; bc1 = bn1;
        __syncthreads();   // next buf staged in all waves; this buf's reads done
    }

    // overlay scratch into ust buffers (free after the GEMM; barrier above protects)
    short* myz = ust[0] + wave * 2176;   // 16 rows x 136
    short* myt = ust[1] + wave * 1152;   // 16 rows x 72

    float zv[7][4];
    float sum = 0.f;
    #pragma unroll
    for (int mt = 0; mt < 7; ++mt) {
        int f0 = mt*16 + l4*4;
        float4 xv = {0,0,0,0};
        if (f0 < 100) xv = *(const float4*)(x + row*100 + f0);
        #pragma unroll
        for (int r = 0; r < 4; ++r) {
            float z = 0.f;
            if (f0 < 100) { z = o[mt][r] + ((const float*)&xv)[r]; sum += z; }
            zv[mt][r] = z;
        }
    }
    sum += __shfl_xor(sum, 16, 64); sum += __shfl_xor(sum, 32, 64);
    float mean = sum * 0.01f;
    float vs = 0.f;
    #pragma unroll
    for (int mt = 0; mt < 7; ++mt) {
        if (mt*16 + l4*4 < 100) {
            #pragma unroll
            for (int r = 0; r < 4; ++r) { float d = zv[mt][r] - mean; vs += d*d; }
        }
    }
    vs += __shfl_xor(vs, 16, 64); vs += __shfl_xor(vs, 32, 64);
    float inv = rsqrtf(vs * 0.01f + 1e-5f);
    float x1r[7][4];
    #pragma unroll
    for (int mt = 0; mt < 7; ++mt) {
        int f0 = mt*16 + l4*4;
        float4 gv = {0,0,0,0}, bv = {0,0,0,0};
        if (f0 < 100) { gv = *(const float4*)(g1 + f0); bv = *(const float4*)(b1 + f0); }
        #pragma unroll
        for (int r = 0; r < 4; ++r)
            x1r[mt][r] = (f0 < 100) ? (zv[mt][r] - mean) * inv * ((const float*)&gv)[r] + ((const float*)&bv)[r] : 0.f;
    }

    #pragma unroll
    for (int mt = 0; mt < 8; ++mt) {
        float v0 = (mt < 7) ? x1r[mt][0] : 0.f, v1 = (mt < 7) ? x1r[mt][1] : 0.f;
        float v2 = (mt < 7) ? x1r[mt][2] : 0.f, v3 = (mt < 7) ? x1r[mt][3] : 0.f;
        st4s(myz + l15*136 + mt*16 + l4*4, pk2bf(v0, v1), pk2bf(v2, v3));
    }
    asm volatile("" ::: "memory");

    float4v t2[4];
    #pragma unroll
    for (int m2t = 0; m2t < 4; ++m2t) t2[m2t] = (float4v){0,0,0,0};
    #pragma unroll
    for (int ks = 0; ks < 4; ++ks) {
        short8 b = *(const short8*)(myz + l15*136 + ks*32 + l4*8);
        #pragma unroll
        for (int m2t = 0; m2t < 4; ++m2t) {
            short8 a = *(const short8*)((const short*)f1wT + (m2t*16 + l15)*128 + ks*32 + l4*8);
            t2[m2t] = __builtin_amdgcn_mfma_f32_16x16x32_bf16(a, b, t2[m2t], 0, 0, 0);
        }
    }
    #pragma unroll
    for (int m2t = 0; m2t < 4; ++m2t) {
        int m20 = m2t*16 + l4*4;
        float4 bv = *(const float4*)(f1b + m20);
        float v0 = fmaxf(t2[m2t][0] + ((const float*)&bv)[0], 0.f);
        float v1 = fmaxf(t2[m2t][1] + ((const float*)&bv)[1], 0.f);
        float v2 = fmaxf(t2[m2t][2] + ((const float*)&bv)[2], 0.f);
        float v3 = fmaxf(t2[m2t][3] + ((const float*)&bv)[3], 0.f);
        st4s(myt + l15*72 + m20, pk2bf(v0, v1), pk2bf(v2, v3));
    }
    asm volatile("" ::: "memory");

    float4v o3[7];
    #pragma unroll
    for (int m3t = 0; m3t < 7; ++m3t) o3[m3t] = (float4v){0,0,0,0};
    #pragma unroll
    for (int ks2 = 0; ks2 < 2; ++ks2) {
        short8 b = *(const short8*)(myt + l15*72 + ks2*32 + l4*8);
        #pragma unroll
        for (int m3t = 0; m3t < 7; ++m3t) {
            short8 a = *(const short8*)((const short*)f2wT + (m3t*16 + l15)*64 + ks2*32 + l4*8);
            o3[m3t] = __builtin_amdgcn_mfma_f32_16x16x32_bf16(a, b, o3[m3t], 0, 0, 0);
        }
    }

    float z2[7][4];
    float sum2 = 0.f;
    #pragma unroll
    for (int m3t = 0; m3t < 7; ++m3t) {
        int f0 = m3t*16 + l4*4;
        float4 bv = {0,0,0,0};
        if (f0 < 100) bv = *(const float4*)(f2b + f0);
        #pragma unroll
        for (int r = 0; r < 4; ++r) {
            float z = 0.f;
            if (f0 < 100) { z = o3[m3t][r] + ((const float*)&bv)[r] + x1r[m3t][r]; sum2 += z; }
            z2[m3t][r] = z;
        }
    }
    sum2 += __shfl_xor(sum2, 16, 64); sum2 += __shfl_xor(sum2, 32, 64);
    float mean2 = sum2 * 0.01f;
    float vs2 = 0.f;
    #pragma unroll
    for (int m3t = 0; m3t < 7; ++m3t) {
        if (m3t*16 + l4*4 < 100) {
            #pragma unroll
            for (int r = 0; r < 4; ++r) { float d = z2[m3t][r] - mean2; vs2 += d*d; }
        }
    }
    vs2 += __shfl_xor(vs2, 16, 64); vs2 += __shfl_xor(vs2, 32, 64);
    float inv2 = rsqrtf(vs2 * 0.01f + 1e-5f);

    unsigned short* xTc = EMIT ? (xT + (long)cc*98304 + ttp) : nullptr;
    #pragma unroll
    for (int m3t = 0; m3t < 7; ++m3t) {
        int f0 = m3t*16 + l4*4;
        if (f0 < 100) {
            float4 gv = *(const float4*)(g2 + f0);
            float4 bv = *(const float4*)(b2 + f0);
            float y[4];
            #pragma unroll
            for (int r = 0; r < 4; ++r)
                y[r] = (z2[m3t][r] - mean2) * inv2 * ((const float*)&gv)[r] + ((const float*)&bv)[r];
            *(float4*)(x + row*100 + f0) = (float4){y[0], y[1], y[2], y[3]};
            if (EMIT) {
                *(uint2v*)(xrow + row*128 + f0) = (uint2v){pk2bf(y[0], y[1]), pk2bf(y[2], y[3])};
                #pragma unroll
                for (int r = 0; r < 4; ++r)
                    xTc[(long)(f0 + r)*768] = f2bf(y[r]);
            }
        } else if (EMIT) {
            *(uint2v*)(xrow + row*128 + f0) = (uint2v){0u, 0u};
            #pragma unroll
            for (int r = 0; r < 4; ++r)
                if (f0 + r < 112) xTc[(long)(f0 + r)*768] = 0;
        }
    }
    if (EMIT) *(uint2v*)(xrow + row*128 + 112 + l4*4) = (uint2v){0u, 0u};
}

// ---------------- autoregressive predictor (composed linear map) ----------------
__global__ void __launch_bounds__(256) k_pred2(const float* __restrict__ xf,
        const float* __restrict__ Mp, const float* __restrict__ c0v,
        float* __restrict__ out) {
    int c = blockIdx.x, tid = threadIdx.x;
    __shared__ float Ml[10000];
    __shared__ float carry[100];
    for (int i = tid; i < 10000; i += 256) Ml[i] = Mp[i];
    if (tid < 100) carry[tid] = xf[((long)c*768 + 767)*100 + tid];
    __syncthreads();
    for (int s = 0; s < 10; ++s) {
        float pv = 0.f;
        if (tid < 100) {
            pv = c0v[tid];
            for (int d = 0; d < 100; ++d) pv += carry[d] * Ml[d*100 + tid];
            out[((long)c*10 + s)*100 + tid] = pv;
        }
        __syncthreads();
        if (tid < 100) carry[tid] = pv;
        __syncthreads();
    }
}

extern "C" void kernel_launch(void* const* d_in, const int* in_sizes, int n_in,
                              void* d_out, int out_size, void* d_ws, size_t ws_size,
                              hipStream_t stream) {
    const float* X    = (const float*)d_in[0];
    const float* A    = (const float*)d_in[1];
    const float* gw1  = (const float*)d_in[2];
    const float* gb1  = (const float*)d_in[3];
    const float* gw2  = (const float*)d_in[4];
    const float* gb2  = (const float*)d_in[5];
    const float* wq   = (const float*)d_in[6];
    const float* wk   = (const float*)d_in[7];
    const float* wv   = (const float*)d_in[8];
    const float* wm   = (const float*)d_in[9];
    const float* f1w  = (const float*)d_in[10];
    const float* f1b  = (const float*)d_in[11];
    const float* f2w  = (const float*)d_in[12];
    const float* f2b  = (const float*)d_in[13];
    const float* ln1g = (const float*)d_in[14];
    const float* ln1b = (const float*)d_in[15];
    const float* ln2g = (const float*)d_in[16];
    const float* ln2b = (const float*)d_in[17];
    const float* l1w  = (const float*)d_in[18];
    const float* l1b  = (const float*)d_in[19];
    const float* l2w  = (const float*)d_in[20];
    const float* l2b  = (const float*)d_in[21];
    (void)in_sizes; (void)n_in; (void)out_size; (void)ws_size;

    float* ws   = (float*)d_ws;
    float* adjh = ws + OFF_ADJ;
    float* x0   = ws + OFF_X0;
    unsigned short* gbuf = (unsigned short*)(ws + OFF_X1);
    unsigned short* hbuf = (unsigned short*)(ws + OFF_X1 + 786432L);
    unsigned short* h2buf= (unsigned short*)(ws + OFF_X1 + 1572864L);
    unsigned short* xrow = (unsigned short*)(ws + OFF_XROW);
    unsigned short* xTb  = (unsigned short*)(ws + OFF_XT);
    unsigned short* Wbf  = (unsigned short*)(ws + OFF_WBF);
    unsigned short* MhT  = (unsigned short*)(ws + OFF_MHT);
    unsigned short* UstT = (unsigned short*)(ws + OFF_USTT);
    float* Mp   = ws + OFF_MP;
    float* c0v  = ws + OFF_C0;
    unsigned short* f1wT = (unsigned short*)(ws + OFF_F1WT);
    unsigned short* f2wT = (unsigned short*)(ws + OFF_F2WT);
    unsigned short* gw1T = (unsigned short*)(ws + OFF_GW1T);
    unsigned short* gw2T = (unsigned short*)(ws + OFF_GW2T);
    float* out  = (float*)d_out;

    k_mu2<<<502, 256, 0, stream>>>(wq, wk, wv, wm, l1w, l1b, l2w, l2b, f1w, f2w, A, gw1, gw2,
                                   MhT, UstT, Mp, c0v, f1wT, f2wT, adjh, gw1T, gw2T);

    // GCN (MFMA weight-gemms; spmms commuted; last spmm emits xrow/xT directly)
    k_gw1<<<768, 128, 0, stream>>>(X, gw1T, gbuf);
    k_spmmg<<<192, 256, 0, stream>>>(adjh, gbuf, gb1, hbuf);
    k_gw2<<<768, 128, 0, stream>>>(hbuf, gw2T, h2buf);
    k_spmmx<<<256, 384, 0, stream>>>(adjh, h2buf, gb2, x0, xrow, xTb);

    // encoder layers: attn + fused tail
    for (int l = 0; l < 3; ++l) {
        k_attn12<<<dim3(6,5,32), 256, 0, stream>>>(xrow, xTb, MhT + (long)l*81920, Wbf);
        if (l < 2)
            k_tail<true><<<768, 128, 0, stream>>>(Wbf, UstT + (long)l*65536,
                f1wT + (long)l*8192, f2wT + (long)l*7168, f1b + l*64, f2b + l*100,
                ln1g + l*100, ln1b + l*100, ln2g + l*100, ln2b + l*100, x0, xrow, xTb);
        else
            k_tail<false><<<768, 128, 0, stream>>>(Wbf, UstT + (long)l*65536,
                f1wT + (long)l*8192, f2wT + (long)l*7168, f1b + l*64, f2b + l*100,
                ln1g + l*100, ln1b + l*100, ln2g + l*100, ln2b + l*100, x0, xrow, xTb);
    }

    k_pred2<<<32, 256, 0, stream>>>(x0, Mp, c0v, out);
}